// Round 1
// 909.503 us; speedup vs baseline: 1.0814x; 1.0814x over previous
//
#include <hip/hip_runtime.h>
#include <math.h>

#define NNODES 50000
#define NEDGES 800000

typedef float v4f __attribute__((ext_vector_type(4)));

// ---------------- CSR build ----------------

__global__ void k_init_cnt(int* __restrict__ cnt) {
    int i = blockIdx.x * 256 + threadIdx.x;
    if (i < NNODES) cnt[i] = 0;
}

__global__ void k_count(const int* __restrict__ dst, int* __restrict__ cnt) {
    int e = blockIdx.x * 256 + threadIdx.x;
    if (e < NEDGES) atomicAdd(&cnt[dst[e]], 1);
}

__global__ void k_dinv(const int* __restrict__ cnt, float* __restrict__ dinv) {
    int i = blockIdx.x * 256 + threadIdx.x;
    if (i < NNODES) dinv[i] = 1.0f / sqrtf((float)cnt[i] + 1.0f);  // +1 self loop
}

// single-block exclusive scan of cnt -> rowptr; also zeroes cnt (reused as cursor)
__global__ __launch_bounds__(1024) void k_scan(int* __restrict__ cnt, int* __restrict__ rowptr) {
    __shared__ int sums[1024];
    const int tid = threadIdx.x;
    const int chunk = (NNODES + 1023) / 1024;   // 49
    const int start = tid * chunk;
    int s = 0;
    for (int i = 0; i < chunk; ++i) {
        int idx = start + i;
        if (idx < NNODES) s += cnt[idx];
    }
    sums[tid] = s;
    __syncthreads();
    for (int off = 1; off < 1024; off <<= 1) {
        int v = 0;
        if (tid >= off) v = sums[tid - off];
        __syncthreads();
        if (tid >= off) sums[tid] += v;
        __syncthreads();
    }
    int run = (tid == 0) ? 0 : sums[tid - 1];   // exclusive base
    for (int i = 0; i < chunk; ++i) {
        int idx = start + i;
        if (idx < NNODES) {
            int v = cnt[idx];
            rowptr[idx] = run;
            run += v;
            cnt[idx] = 0;                        // reset for fill-cursor use
        }
    }
    if (tid == 1023) rowptr[NNODES] = run;       // == NEDGES
}

__global__ void k_fill(const int* __restrict__ src, const int* __restrict__ dst,
                       const int* __restrict__ rowptr, int* __restrict__ cursor,
                       const float* __restrict__ dinv,
                       int* __restrict__ col, float* __restrict__ val) {
    int e = blockIdx.x * 256 + threadIdx.x;
    if (e < NEDGES) {
        int s = src[e], d = dst[e];
        int pos = rowptr[d] + atomicAdd(&cursor[d], 1);
        col[pos] = s;
        val[pos] = dinv[s] * dinv[d];
    }
}

// ---------------- fp32 tiled GEMM ----------------
// C[M,Ncols] = A[M,K] @ W[K,Ncols] (+ bias) (+ optional relu).  256 threads,
// TM x TN microtile.  Thread's TN columns are split into TN/4 float4 chunks
// spaced SN=BN/(TN/4) apart: each b-read instruction touches a contiguous
// 256B LDS region -> 2-way bank aliasing only (free on gfx950, m136).
// Grid is 1-D MB*NB with n-block fastest so column-blocks sharing A rows are
// co-resident (A stays in L2/LLC).

template<int BM, int BN, int BK, int TM, int TN, bool NT, bool RELU>
__global__ __launch_bounds__(256) void k_gemm(const float* __restrict__ A,
                                              const float* __restrict__ W,
                                              const float* __restrict__ bias,
                                              float* __restrict__ C,
                                              int M, int Ncols, int K, int NB) {
    __shared__ __align__(16) float As[BK][BM];   // transposed A tile
    __shared__ __align__(16) float Ws[BK][BN];

    constexpr int CHN = TN / 4;        // float4 chunks per thread (cols)
    constexpr int SN  = BN / CHN;      // column stride between chunks
    constexpr int NTX = SN / 4;        // thread-columns (=16 for our configs)

    const int tid = threadIdx.x;
    const int tx = tid % NTX;
    const int ty = tid / NTX;
    const int bid = blockIdx.x;
    const int m0 = (bid / NB) * BM;
    const int n0 = (bid % NB) * BN;

    float acc[TM][TN];
#pragma unroll
    for (int i = 0; i < TM; ++i)
#pragma unroll
        for (int j = 0; j < TN; ++j) acc[i][j] = 0.0f;

    constexpr int AITER = (BM * BK / 4) / 256;
    constexpr int WITER = (BK * BN / 4) / 256;

    for (int k0 = 0; k0 < K; k0 += BK) {
#pragma unroll
        for (int it = 0; it < AITER; ++it) {
            int f4 = tid + it * 256;
            int row = f4 / (BK / 4);
            int kk = (f4 % (BK / 4)) * 4;
            float4 v = make_float4(0.f, 0.f, 0.f, 0.f);
            int gr = m0 + row;
            if (gr < M) v = *(const float4*)&A[(size_t)gr * K + k0 + kk];
            As[kk + 0][row] = v.x;
            As[kk + 1][row] = v.y;
            As[kk + 2][row] = v.z;
            As[kk + 3][row] = v.w;
        }
#pragma unroll
        for (int it = 0; it < WITER; ++it) {
            int f4 = tid + it * 256;
            int kk = f4 / (BN / 4);
            int nn = (f4 % (BN / 4)) * 4;
            *(float4*)&Ws[kk][nn] = *(const float4*)&W[(size_t)(k0 + kk) * Ncols + n0 + nn];
        }
        __syncthreads();

#pragma unroll
        for (int kk = 0; kk < BK; ++kk) {
            float a[TM], b[TN];
#pragma unroll
            for (int i = 0; i < TM; i += 4)
                *(float4*)&a[i] = *(const float4*)&As[kk][ty * TM + i];
#pragma unroll
            for (int c = 0; c < CHN; ++c)
                *(float4*)&b[c * 4] = *(const float4*)&Ws[kk][c * SN + tx * 4];
#pragma unroll
            for (int i = 0; i < TM; ++i)
#pragma unroll
                for (int j = 0; j < TN; ++j)
                    acc[i][j] = fmaf(a[i], b[j], acc[i][j]);
        }
        __syncthreads();
    }

#pragma unroll
    for (int i = 0; i < TM; ++i) {
        int gr = m0 + ty * TM + i;
        if (gr < M) {
#pragma unroll
            for (int c = 0; c < CHN; ++c) {
                int nb = n0 + c * SN + tx * 4;
                float4 v;
                v.x = acc[i][c * 4 + 0];
                v.y = acc[i][c * 4 + 1];
                v.z = acc[i][c * 4 + 2];
                v.w = acc[i][c * 4 + 3];
                if (bias != nullptr) {
                    v.x += bias[nb + 0];
                    v.y += bias[nb + 1];
                    v.z += bias[nb + 2];
                    v.w += bias[nb + 3];
                }
                if (RELU) {
                    v.x = fmaxf(v.x, 0.f);
                    v.y = fmaxf(v.y, 0.f);
                    v.z = fmaxf(v.z, 0.f);
                    v.w = fmaxf(v.w, 0.f);
                }
                if (NT) {
                    v4f nv;
                    nv.x = v.x; nv.y = v.y; nv.z = v.z; nv.w = v.w;
                    __builtin_nontemporal_store(nv, (v4f*)&C[(size_t)gr * Ncols + nb]);
                } else {
                    *(float4*)&C[(size_t)gr * Ncols + nb] = v;
                }
            }
        }
    }
}

// ---------------- CSR SpMM (aggregation + self loop + optional bias/relu) ----
// out[row] = sum_{e in row} H[col[e]] * val[e] + H[row]*dinv[row]^2 (+ bias)
// Edge loop unrolled x8: batches 8 gathers in flight (latency-bound otherwise).

template<int CH, bool RELU, bool HB>
__global__ __launch_bounds__(256) void k_spmm(const float* __restrict__ H,
                                              const float* __restrict__ dinv,
                                              const int* __restrict__ rowptr,
                                              const int* __restrict__ col,
                                              const float* __restrict__ val,
                                              const float* __restrict__ bias,
                                              float* __restrict__ out) {
    constexpr int CV = CH / 4;
    int t = blockIdx.x * 256 + threadIdx.x;
    int row = t / CV;
    if (row >= NNODES) return;
    int c = (t % CV) * 4;

    float dv = dinv[row];
    float s2 = dv * dv;
    float4 h = *(const float4*)&H[(size_t)row * CH + c];
    float ax, ay, az, aw;
    if (HB) {
        float4 b = *(const float4*)&bias[c];
        ax = fmaf(h.x, s2, b.x);
        ay = fmaf(h.y, s2, b.y);
        az = fmaf(h.z, s2, b.z);
        aw = fmaf(h.w, s2, b.w);
    } else {
        ax = h.x * s2;
        ay = h.y * s2;
        az = h.z * s2;
        aw = h.w * s2;
    }

    const int e0 = rowptr[row], e1 = rowptr[row + 1];
    int e = e0;
    for (; e + 8 <= e1; e += 8) {
        int s[8];
        float w[8];
#pragma unroll
        for (int u = 0; u < 8; ++u) { s[u] = col[e + u]; w[u] = val[e + u]; }
        float4 hv[8];
#pragma unroll
        for (int u = 0; u < 8; ++u)
            hv[u] = *(const float4*)&H[(size_t)s[u] * CH + c];
#pragma unroll
        for (int u = 0; u < 8; ++u) {
            ax = fmaf(hv[u].x, w[u], ax);
            ay = fmaf(hv[u].y, w[u], ay);
            az = fmaf(hv[u].z, w[u], az);
            aw = fmaf(hv[u].w, w[u], aw);
        }
    }
    for (; e < e1; ++e) {
        int sidx = col[e];
        float w = val[e];
        float4 hv = *(const float4*)&H[(size_t)sidx * CH + c];
        ax = fmaf(hv.x, w, ax);
        ay = fmaf(hv.y, w, ay);
        az = fmaf(hv.z, w, az);
        aw = fmaf(hv.w, w, aw);
    }
    if (RELU) {
        ax = fmaxf(ax, 0.f);
        ay = fmaxf(ay, 0.f);
        az = fmaxf(az, 0.f);
        aw = fmaxf(aw, 0.f);
    }
    float4 o;
    o.x = ax; o.y = ay; o.z = az; o.w = aw;
    *(float4*)&out[(size_t)row * CH + c] = o;
}

// ---------------- launcher ----------------

extern "C" void kernel_launch(void* const* d_in, const int* in_sizes, int n_in,
                              void* d_out, int out_size, void* d_ws, size_t ws_size,
                              hipStream_t stream) {
    const float* x   = (const float*)d_in[0];
    const int*   ei  = (const int*)d_in[1];
    const float* eW1 = (const float*)d_in[2];
    const float* eb1 = (const float*)d_in[3];
    const float* eW2 = (const float*)d_in[4];
    const float* eb2 = (const float*)d_in[5];
    const float* eWf = (const float*)d_in[6];
    const float* ebf = (const float*)d_in[7];
    const float* dW1 = (const float*)d_in[8];
    const float* db1 = (const float*)d_in[9];
    const float* dW2 = (const float*)d_in[10];
    const float* db2 = (const float*)d_in[11];
    const float* dWf = (const float*)d_in[12];
    const float* dbf = (const float*)d_in[13];
    float* out = (float*)d_out;

    char* ws = (char*)d_ws;
    size_t off = 0;
    auto alloc = [&](size_t bytes) { size_t r = off; off += (bytes + 255) & ~(size_t)255; return r; };
    float* dinv   = (float*)(ws + alloc((size_t)NNODES * 4));
    int*   cnt    = (int*)  (ws + alloc((size_t)NNODES * 4));
    int*   rowptr = (int*)  (ws + alloc((size_t)(NNODES + 1) * 4));
    int*   col    = (int*)  (ws + alloc((size_t)NEDGES * 4));
    float* val    = (float*)(ws + alloc((size_t)NEDGES * 4));
    float* B1     = (float*)(ws + alloc((size_t)NNODES * 256 * 4));
    // B2 aliases the front of d_out (204.8 MB total; B2 needs <=51.2 MB).
    // Its last read (A4 spmm) completes before the final GEMM writes d_out.
    float* B2 = out;

    const int* src = ei;
    const int* dst = ei + NEDGES;

    const int gN = (NNODES + 255) / 256;
    const int gE = (NEDGES + 255) / 256;

    k_init_cnt<<<gN, 256, 0, stream>>>(cnt);
    k_count<<<gE, 256, 0, stream>>>(dst, cnt);
    k_dinv<<<gN, 256, 0, stream>>>(cnt, dinv);
    k_scan<<<1, 1024, 0, stream>>>(cnt, rowptr);
    k_fill<<<gE, 256, 0, stream>>>(src, dst, rowptr, cnt, dinv, col, val);

    const int MB = (NNODES + 127) / 128;   // 391 row-blocks

    // Encoder:
    // H1 = x @ eW1  [50000,128]x[128,128] -> B1
    k_gemm<128,128,16,8,8,false,false><<<MB, 256, 0, stream>>>(x, eW1, nullptr, B1, NNODES, 128, 128, 1);
    // A1 = relu(agg(H1) + eb1) -> B2   (agg at 128 ch)
    k_spmm<128,true,true><<<(NNODES * 32 + 255) / 256, 256, 0, stream>>>(B1, dinv, rowptr, col, val, eb1, B2);
    // H2 = A1 @ eW2  [128->64] -> B1
    k_gemm<128,64,16,8,4,false,false><<<MB, 256, 0, stream>>>(B2, eW2, nullptr, B1, NNODES, 64, 128, 1);
    // A2 = agg(H2) + eb2 -> B2         (agg at 64 ch)
    k_spmm<64,false,true><<<(NNODES * 16 + 255) / 256, 256, 0, stream>>>(B1, dinv, rowptr, col, val, eb2, B2);
    // Z = A2 @ eWf + ebf -> B1  [50000,64]
    k_gemm<128,64,16,8,4,false,false><<<MB, 256, 0, stream>>>(B2, eWf, ebf, B1, NNODES, 64, 64, 1);

    // Decoder layer 1, reassociated:  relu(agg(Z @ dW1) + db1) == relu(agg(Z) @ dW1 + db1)
    // (aggregation is linear and commutes with the right-multiply; this moves the
    //  800k-edge gather from 256 ch (819 MB) down to 64 ch (205 MB)).
    // G = agg(Z) -> B2                 (agg at 64 ch, NO bias)
    k_spmm<64,false,false><<<(NNODES * 16 + 255) / 256, 256, 0, stream>>>(B1, dinv, rowptr, col, val, nullptr, B2);
    // A3 = relu(G @ dW1 + db1) -> B1  [50000,256]  (bias+relu fused in epilogue)
    k_gemm<128,128,16,8,8,false,true><<<MB * 2, 256, 0, stream>>>(B2, dW1, db1, B1, NNODES, 256, 64, 2);

    // Decoder layer 2 (already aggregates on the narrow side: 128 < 256):
    // H4 = A3 @ dW2  [256->128] -> B2
    k_gemm<128,128,16,8,8,false,false><<<MB, 256, 0, stream>>>(B1, dW2, nullptr, B2, NNODES, 128, 256, 1);
    // A4 = agg(H4) + db2 -> B1         (agg at 128 ch)
    k_spmm<128,false,true><<<(NNODES * 32 + 255) / 256, 256, 0, stream>>>(B2, dinv, rowptr, col, val, db2, B1);
    // x_hat = A4 @ dWf + dbf -> d_out  [50000,1024]  (nontemporal C stores)
    k_gemm<128,128,16,8,8,true,false><<<MB * 8, 256, 0, stream>>>(B1, dWf, dbf, out, NNODES, 1024, 128, 8);
}

// Round 2
// 843.389 us; speedup vs baseline: 1.1662x; 1.0784x over previous
//
#include <hip/hip_runtime.h>
#include <math.h>

#define NNODES 50000
#define NEDGES 800000

typedef float v4f __attribute__((ext_vector_type(4)));
typedef short bf16x8 __attribute__((ext_vector_type(8)));
typedef float f32x4 __attribute__((ext_vector_type(4)));
typedef unsigned short u16x4 __attribute__((ext_vector_type(4)));

// bf16 round-to-nearest-even helpers
__device__ __forceinline__ unsigned short f2bf(float f) {
    unsigned u = __float_as_uint(f);
    return (unsigned short)((u + 0x7fff + ((u >> 16) & 1)) >> 16);
}
__device__ __forceinline__ float bf2f(unsigned short h) {
    return __uint_as_float(((unsigned)h) << 16);
}

// ---------------- CSR build ----------------

__global__ void k_init_cnt(int* __restrict__ cnt) {
    int i = blockIdx.x * 256 + threadIdx.x;
    if (i < NNODES) cnt[i] = 0;
}

__global__ void k_count(const int* __restrict__ dst, int* __restrict__ cnt) {
    int e = blockIdx.x * 256 + threadIdx.x;
    if (e < NEDGES) atomicAdd(&cnt[dst[e]], 1);
}

__global__ void k_dinv(const int* __restrict__ cnt, float* __restrict__ dinv) {
    int i = blockIdx.x * 256 + threadIdx.x;
    if (i < NNODES) dinv[i] = 1.0f / sqrtf((float)cnt[i] + 1.0f);  // +1 self loop
}

// single-block exclusive scan of cnt -> rowptr; also zeroes cnt (reused as cursor)
__global__ __launch_bounds__(1024) void k_scan(int* __restrict__ cnt, int* __restrict__ rowptr) {
    __shared__ int sums[1024];
    const int tid = threadIdx.x;
    const int chunk = (NNODES + 1023) / 1024;   // 49
    const int start = tid * chunk;
    int s = 0;
    for (int i = 0; i < chunk; ++i) {
        int idx = start + i;
        if (idx < NNODES) s += cnt[idx];
    }
    sums[tid] = s;
    __syncthreads();
    for (int off = 1; off < 1024; off <<= 1) {
        int v = 0;
        if (tid >= off) v = sums[tid - off];
        __syncthreads();
        if (tid >= off) sums[tid] += v;
        __syncthreads();
    }
    int run = (tid == 0) ? 0 : sums[tid - 1];   // exclusive base
    for (int i = 0; i < chunk; ++i) {
        int idx = start + i;
        if (idx < NNODES) {
            int v = cnt[idx];
            rowptr[idx] = run;
            run += v;
            cnt[idx] = 0;                        // reset for fill-cursor use
        }
    }
    if (tid == 1023) rowptr[NNODES] = run;       // == NEDGES
}

__global__ void k_fill(const int* __restrict__ src, const int* __restrict__ dst,
                       const int* __restrict__ rowptr, int* __restrict__ cursor,
                       const float* __restrict__ dinv,
                       int* __restrict__ col, float* __restrict__ val) {
    int e = blockIdx.x * 256 + threadIdx.x;
    if (e < NEDGES) {
        int s = src[e], d = dst[e];
        int pos = rowptr[d] + atomicAdd(&cursor[d], 1);
        col[pos] = s;
        val[pos] = dinv[s] * dinv[d];
    }
}

// ---------------- W split+permute for MFMA B-fragments ----------------
// W[128][1024] fp32 -> Wh/Wl bf16 in fragment order:
// slot (kt, nt, lane, j) holds W[kt*32 + (lane>>4)*8 + j][nt*16 + (lane&15)]
// so the GEMM's B-frag is ONE coalesced 16B load per lane.

__global__ void k_wsplit(const float* __restrict__ W, unsigned short* __restrict__ Wh,
                         unsigned short* __restrict__ Wl) {
    int idx = blockIdx.x * 256 + threadIdx.x;
    if (idx >= 128 * 1024) return;
    int k = idx >> 10;          // 0..127
    int n = idx & 1023;
    float a = W[idx];
    unsigned short h = f2bf(a);
    unsigned short l = f2bf(a - bf2f(h));
    int kt = k >> 5, kr = k & 31;
    int g = kr >> 3, j = kr & 7;
    int nt = n >> 4, nc = n & 15;
    int lane = g * 16 + nc;
    size_t off = ((size_t)(kt * 64 + nt) * 64 + lane) * 8 + j;
    Wh[off] = h;
    Wl[off] = l;
}

// ---------------- fp32 tiled GEMM (unchanged core) ----------------

template<int BM, int BN, int BK, int TM, int TN, bool NT, bool RELU>
__global__ __launch_bounds__(256) void k_gemm(const float* __restrict__ A,
                                              const float* __restrict__ W,
                                              const float* __restrict__ bias,
                                              float* __restrict__ C,
                                              int M, int Ncols, int K, int NB) {
    __shared__ __align__(16) float As[BK][BM];   // transposed A tile
    __shared__ __align__(16) float Ws[BK][BN];

    constexpr int CHN = TN / 4;        // float4 chunks per thread (cols)
    constexpr int SN  = BN / CHN;      // column stride between chunks
    constexpr int NTX = SN / 4;        // thread-columns

    const int tid = threadIdx.x;
    const int tx = tid % NTX;
    const int ty = tid / NTX;
    const int bid = blockIdx.x;
    const int m0 = (bid / NB) * BM;
    const int n0 = (bid % NB) * BN;

    float acc[TM][TN];
#pragma unroll
    for (int i = 0; i < TM; ++i)
#pragma unroll
        for (int j = 0; j < TN; ++j) acc[i][j] = 0.0f;

    constexpr int AITER = (BM * BK / 4) / 256;
    constexpr int WITER = (BK * BN / 4) / 256;

    for (int k0 = 0; k0 < K; k0 += BK) {
#pragma unroll
        for (int it = 0; it < AITER; ++it) {
            int f4 = tid + it * 256;
            int row = f4 / (BK / 4);
            int kk = (f4 % (BK / 4)) * 4;
            float4 v = make_float4(0.f, 0.f, 0.f, 0.f);
            int gr = m0 + row;
            if (gr < M) v = *(const float4*)&A[(size_t)gr * K + k0 + kk];
            As[kk + 0][row] = v.x;
            As[kk + 1][row] = v.y;
            As[kk + 2][row] = v.z;
            As[kk + 3][row] = v.w;
        }
#pragma unroll
        for (int it = 0; it < WITER; ++it) {
            int f4 = tid + it * 256;
            int kk = f4 / (BN / 4);
            int nn = (f4 % (BN / 4)) * 4;
            *(float4*)&Ws[kk][nn] = *(const float4*)&W[(size_t)(k0 + kk) * Ncols + n0 + nn];
        }
        __syncthreads();

#pragma unroll
        for (int kk = 0; kk < BK; ++kk) {
            float a[TM], b[TN];
#pragma unroll
            for (int i = 0; i < TM; i += 4)
                *(float4*)&a[i] = *(const float4*)&As[kk][ty * TM + i];
#pragma unroll
            for (int c = 0; c < CHN; ++c)
                *(float4*)&b[c * 4] = *(const float4*)&Ws[kk][c * SN + tx * 4];
#pragma unroll
            for (int i = 0; i < TM; ++i)
#pragma unroll
                for (int j = 0; j < TN; ++j)
                    acc[i][j] = fmaf(a[i], b[j], acc[i][j]);
        }
        __syncthreads();
    }

#pragma unroll
    for (int i = 0; i < TM; ++i) {
        int gr = m0 + ty * TM + i;
        if (gr < M) {
#pragma unroll
            for (int c = 0; c < CHN; ++c) {
                int nb = n0 + c * SN + tx * 4;
                float4 v;
                v.x = acc[i][c * 4 + 0];
                v.y = acc[i][c * 4 + 1];
                v.z = acc[i][c * 4 + 2];
                v.w = acc[i][c * 4 + 3];
                if (bias != nullptr) {
                    v.x += bias[nb + 0];
                    v.y += bias[nb + 1];
                    v.z += bias[nb + 2];
                    v.w += bias[nb + 3];
                }
                if (RELU) {
                    v.x = fmaxf(v.x, 0.f);
                    v.y = fmaxf(v.y, 0.f);
                    v.z = fmaxf(v.z, 0.f);
                    v.w = fmaxf(v.w, 0.f);
                }
                if (NT) {
                    v4f nv;
                    nv.x = v.x; nv.y = v.y; nv.z = v.z; nv.w = v.w;
                    __builtin_nontemporal_store(nv, (v4f*)&C[(size_t)gr * Ncols + nb]);
                } else {
                    *(float4*)&C[(size_t)gr * Ncols + nb] = v;
                }
            }
        }
    }
}

// ---------------- MFMA bf16-split GEMM for the final layer ----------------
// C[M,1024] = (Ah+Al)[M,128] @ (Wh+Wl)[128,1024] + bias, fp32 accumulate.
// 3-product split: Ah*Wh + Ah*Wl + Al*Wh (Al*Wl ~2^-18, dropped).
// No LDS: A-frags are contiguous 16B loads from row-major bf16; W is
// pre-permuted (k_wsplit) into exact B-fragment order and stays L2-hot.
// Block=256 (4 waves, 2x2), tile 128x128, per-wave 64x64 = 4x4 16x16 frags.

__global__ __launch_bounds__(256) void k_gemm_mfma_k128(
        const unsigned short* __restrict__ Ah, const unsigned short* __restrict__ Al,
        const unsigned short* __restrict__ Wh, const unsigned short* __restrict__ Wl,
        const float* __restrict__ bias, float* __restrict__ C, int M, int Ncols) {
    const int lane = threadIdx.x & 63;
    const int wave = threadIdx.x >> 6;
    const int wr = wave >> 1, wc = wave & 1;
    const int l15 = lane & 15, l4 = lane >> 4;
    const int bid = blockIdx.x;
    const int NB = Ncols >> 7;                // n-fastest: A-tile reuse in L2
    const int m0 = (bid / NB) * 128;
    const int n0 = (bid % NB) * 128;

    f32x4 acc[4][4];
#pragma unroll
    for (int i = 0; i < 4; ++i)
#pragma unroll
        for (int j = 0; j < 4; ++j) {
            f32x4 z = {0.f, 0.f, 0.f, 0.f};
            acc[i][j] = z;
        }

    int arow[4];
#pragma unroll
    for (int mf = 0; mf < 4; ++mf) {
        int r = m0 + wr * 64 + mf * 16 + l15;
        arow[mf] = r < M ? r : M - 1;         // clamp: OOB rows never stored
    }
    const int ntbase = (n0 + wc * 64) >> 4;

#pragma unroll
    for (int kt = 0; kt < 4; ++kt) {
        bf16x8 ah[4], al[4], bh[4], bl[4];
        const int ka = kt * 32 + l4 * 8;
#pragma unroll
        for (int mf = 0; mf < 4; ++mf) {
            ah[mf] = *(const bf16x8*)&Ah[(size_t)arow[mf] * 128 + ka];
            al[mf] = *(const bf16x8*)&Al[(size_t)arow[mf] * 128 + ka];
        }
#pragma unroll
        for (int nf = 0; nf < 4; ++nf) {
            size_t off = ((size_t)(kt * 64 + ntbase + nf) * 64 + lane) * 8;
            bh[nf] = *(const bf16x8*)&Wh[off];
            bl[nf] = *(const bf16x8*)&Wl[off];
        }
#pragma unroll
        for (int mf = 0; mf < 4; ++mf)
#pragma unroll
            for (int nf = 0; nf < 4; ++nf) {
                acc[mf][nf] = __builtin_amdgcn_mfma_f32_16x16x32_bf16(ah[mf], bh[nf], acc[mf][nf], 0, 0, 0);
                acc[mf][nf] = __builtin_amdgcn_mfma_f32_16x16x32_bf16(ah[mf], bl[nf], acc[mf][nf], 0, 0, 0);
                acc[mf][nf] = __builtin_amdgcn_mfma_f32_16x16x32_bf16(al[mf], bh[nf], acc[mf][nf], 0, 0, 0);
            }
    }

    float bv[4];
#pragma unroll
    for (int nf = 0; nf < 4; ++nf) bv[nf] = bias[n0 + wc * 64 + nf * 16 + l15];

    // C/D layout (m89-verified): col = lane&15, row = (lane>>4)*4 + reg
#pragma unroll
    for (int mf = 0; mf < 4; ++mf) {
        int gr0 = m0 + wr * 64 + mf * 16 + l4 * 4;
#pragma unroll
        for (int r = 0; r < 4; ++r) {
            int gr = gr0 + r;
            if (gr < M) {
#pragma unroll
                for (int nf = 0; nf < 4; ++nf) {
                    float v = acc[mf][nf][r] + bv[nf];
                    __builtin_nontemporal_store(v, &C[(size_t)gr * Ncols + n0 + wc * 64 + nf * 16 + l15]);
                }
            }
        }
    }
}

// ---------------- CSR SpMM (aggregation + self loop + optional bias/relu) ----

template<int CH, bool RELU, bool HB>
__global__ __launch_bounds__(256) void k_spmm(const float* __restrict__ H,
                                              const float* __restrict__ dinv,
                                              const int* __restrict__ rowptr,
                                              const int* __restrict__ col,
                                              const float* __restrict__ val,
                                              const float* __restrict__ bias,
                                              float* __restrict__ out) {
    constexpr int CV = CH / 4;
    int t = blockIdx.x * 256 + threadIdx.x;
    int row = t / CV;
    if (row >= NNODES) return;
    int c = (t % CV) * 4;

    float dv = dinv[row];
    float s2 = dv * dv;
    float4 h = *(const float4*)&H[(size_t)row * CH + c];
    float ax, ay, az, aw;
    if (HB) {
        float4 b = *(const float4*)&bias[c];
        ax = fmaf(h.x, s2, b.x);
        ay = fmaf(h.y, s2, b.y);
        az = fmaf(h.z, s2, b.z);
        aw = fmaf(h.w, s2, b.w);
    } else {
        ax = h.x * s2;
        ay = h.y * s2;
        az = h.z * s2;
        aw = h.w * s2;
    }

    const int e0 = rowptr[row], e1 = rowptr[row + 1];
    int e = e0;
    for (; e + 8 <= e1; e += 8) {
        int s[8];
        float w[8];
#pragma unroll
        for (int u = 0; u < 8; ++u) { s[u] = col[e + u]; w[u] = val[e + u]; }
        float4 hv[8];
#pragma unroll
        for (int u = 0; u < 8; ++u)
            hv[u] = *(const float4*)&H[(size_t)s[u] * CH + c];
#pragma unroll
        for (int u = 0; u < 8; ++u) {
            ax = fmaf(hv[u].x, w[u], ax);
            ay = fmaf(hv[u].y, w[u], ay);
            az = fmaf(hv[u].z, w[u], az);
            aw = fmaf(hv[u].w, w[u], aw);
        }
    }
    for (; e < e1; ++e) {
        int sidx = col[e];
        float w = val[e];
        float4 hv = *(const float4*)&H[(size_t)sidx * CH + c];
        ax = fmaf(hv.x, w, ax);
        ay = fmaf(hv.y, w, ay);
        az = fmaf(hv.z, w, az);
        aw = fmaf(hv.w, w, aw);
    }
    if (RELU) {
        ax = fmaxf(ax, 0.f);
        ay = fmaxf(ay, 0.f);
        az = fmaxf(az, 0.f);
        aw = fmaxf(aw, 0.f);
    }
    float4 o;
    o.x = ax; o.y = ay; o.z = az; o.w = aw;
    *(float4*)&out[(size_t)row * CH + c] = o;
}

// ---- SpMM variant for A4 (CH=128, bias, no relu) that writes the bf16
// hi/lo split directly (feeds the MFMA final GEMM; fp32 A4 never hits HBM).

__global__ __launch_bounds__(256) void k_spmm_split(const float* __restrict__ H,
                                                    const float* __restrict__ dinv,
                                                    const int* __restrict__ rowptr,
                                                    const int* __restrict__ col,
                                                    const float* __restrict__ val,
                                                    const float* __restrict__ bias,
                                                    unsigned short* __restrict__ Ah,
                                                    unsigned short* __restrict__ Al) {
    int t = blockIdx.x * 256 + threadIdx.x;
    int row = t / 32;
    if (row >= NNODES) return;
    int c = (t % 32) * 4;

    float dv = dinv[row];
    float s2 = dv * dv;
    float4 h = *(const float4*)&H[(size_t)row * 128 + c];
    float4 b = *(const float4*)&bias[c];
    float ax = fmaf(h.x, s2, b.x);
    float ay = fmaf(h.y, s2, b.y);
    float az = fmaf(h.z, s2, b.z);
    float aw = fmaf(h.w, s2, b.w);

    const int e0 = rowptr[row], e1 = rowptr[row + 1];
    int e = e0;
    for (; e + 8 <= e1; e += 8) {
        int s[8];
        float w[8];
#pragma unroll
        for (int u = 0; u < 8; ++u) { s[u] = col[e + u]; w[u] = val[e + u]; }
        float4 hv[8];
#pragma unroll
        for (int u = 0; u < 8; ++u)
            hv[u] = *(const float4*)&H[(size_t)s[u] * 128 + c];
#pragma unroll
        for (int u = 0; u < 8; ++u) {
            ax = fmaf(hv[u].x, w[u], ax);
            ay = fmaf(hv[u].y, w[u], ay);
            az = fmaf(hv[u].z, w[u], az);
            aw = fmaf(hv[u].w, w[u], aw);
        }
    }
    for (; e < e1; ++e) {
        int sidx = col[e];
        float w = val[e];
        float4 hv = *(const float4*)&H[(size_t)sidx * 128 + c];
        ax = fmaf(hv.x, w, ax);
        ay = fmaf(hv.y, w, ay);
        az = fmaf(hv.z, w, az);
        aw = fmaf(hv.w, w, aw);
    }

    u16x4 hvv, lvv;
    hvv.x = f2bf(ax); lvv.x = f2bf(ax - bf2f(hvv.x));
    hvv.y = f2bf(ay); lvv.y = f2bf(ay - bf2f(hvv.y));
    hvv.z = f2bf(az); lvv.z = f2bf(az - bf2f(hvv.z));
    hvv.w = f2bf(aw); lvv.w = f2bf(aw - bf2f(hvv.w));
    *(u16x4*)&Ah[(size_t)row * 128 + c] = hvv;
    *(u16x4*)&Al[(size_t)row * 128 + c] = lvv;
}

// ---------------- launcher ----------------

extern "C" void kernel_launch(void* const* d_in, const int* in_sizes, int n_in,
                              void* d_out, int out_size, void* d_ws, size_t ws_size,
                              hipStream_t stream) {
    const float* x   = (const float*)d_in[0];
    const int*   ei  = (const int*)d_in[1];
    const float* eW1 = (const float*)d_in[2];
    const float* eb1 = (const float*)d_in[3];
    const float* eW2 = (const float*)d_in[4];
    const float* eb2 = (const float*)d_in[5];
    const float* eWf = (const float*)d_in[6];
    const float* ebf = (const float*)d_in[7];
    const float* dW1 = (const float*)d_in[8];
    const float* db1 = (const float*)d_in[9];
    const float* dW2 = (const float*)d_in[10];
    const float* db2 = (const float*)d_in[11];
    const float* dWf = (const float*)d_in[12];
    const float* dbf = (const float*)d_in[13];
    float* out = (float*)d_out;

    char* ws = (char*)d_ws;
    size_t off = 0;
    auto alloc = [&](size_t bytes) { size_t r = off; off += (bytes + 255) & ~(size_t)255; return r; };
    float* dinv   = (float*)(ws + alloc((size_t)NNODES * 4));
    int*   cnt    = (int*)  (ws + alloc((size_t)NNODES * 4));
    int*   rowptr = (int*)  (ws + alloc((size_t)(NNODES + 1) * 4));
    int*   col    = (int*)  (ws + alloc((size_t)NEDGES * 4));
    float* val    = (float*)(ws + alloc((size_t)NEDGES * 4));
    float* B1     = (float*)(ws + alloc((size_t)NNODES * 256 * 4));
    unsigned short* Whp = (unsigned short*)(ws + alloc((size_t)128 * 1024 * 2));
    unsigned short* Wlp = (unsigned short*)(ws + alloc((size_t)128 * 1024 * 2));
    // Ah/Al (bf16 split of A4, 12.8 MB each) alias B1: A3 (which filled B1)
    // is dead once H4 is computed, and the A4-spmm writes only these.
    unsigned short* Ah = (unsigned short*)B1;
    unsigned short* Al = (unsigned short*)((char*)B1 + (size_t)NNODES * 128 * 2);
    // B2 aliases the front of d_out (204.8 MB total; B2 needs <=51.2 MB).
    float* B2 = out;

    const int* src = ei;
    const int* dst = ei + NEDGES;

    const int gN = (NNODES + 255) / 256;
    const int gE = (NEDGES + 255) / 256;

    k_init_cnt<<<gN, 256, 0, stream>>>(cnt);
    k_count<<<gE, 256, 0, stream>>>(dst, cnt);
    k_dinv<<<gN, 256, 0, stream>>>(cnt, dinv);
    k_scan<<<1, 1024, 0, stream>>>(cnt, rowptr);
    k_fill<<<gE, 256, 0, stream>>>(src, dst, rowptr, cnt, dinv, col, val);
    // W split+permute for the final GEMM (no pipeline deps; 512 KB)
    k_wsplit<<<(128 * 1024 + 255) / 256, 256, 0, stream>>>(dWf, Whp, Wlp);

    const int MB = (NNODES + 127) / 128;   // 391 row-blocks

    // Encoder:
    // H1 = x @ eW1  [50000,128]x[128,128] -> B1
    k_gemm<128,128,16,8,8,false,false><<<MB, 256, 0, stream>>>(x, eW1, nullptr, B1, NNODES, 128, 128, 1);
    // A1 = relu(agg(H1) + eb1) -> B2   (agg at 128 ch)
    k_spmm<128,true,true><<<(NNODES * 32 + 255) / 256, 256, 0, stream>>>(B1, dinv, rowptr, col, val, eb1, B2);
    // H2 = A1 @ eW2  [128->64] -> B1
    k_gemm<128,64,16,8,4,false,false><<<MB, 256, 0, stream>>>(B2, eW2, nullptr, B1, NNODES, 64, 128, 1);
    // A2 = agg(H2) + eb2 -> B2         (agg at 64 ch)
    k_spmm<64,false,true><<<(NNODES * 16 + 255) / 256, 256, 0, stream>>>(B1, dinv, rowptr, col, val, eb2, B2);
    // Z = A2 @ eWf + ebf -> B1  [50000,64]
    k_gemm<128,64,16,8,4,false,false><<<MB, 256, 0, stream>>>(B2, eWf, ebf, B1, NNODES, 64, 64, 1);

    // Decoder layer 1 (reassociated): relu(agg(Z) @ dW1 + db1)
    // G = agg(Z) -> B2                 (agg at 64 ch, NO bias)
    k_spmm<64,false,false><<<(NNODES * 16 + 255) / 256, 256, 0, stream>>>(B1, dinv, rowptr, col, val, nullptr, B2);
    // A3 = relu(G @ dW1 + db1) -> B1  [50000,256]  (bias+relu fused)
    k_gemm<128,128,16,8,8,false,true><<<MB * 2, 256, 0, stream>>>(B2, dW1, db1, B1, NNODES, 256, 64, 2);

    // Decoder layer 2:
    // H4 = A3 @ dW2  [256->128] -> B2
    k_gemm<128,128,16,8,8,false,false><<<MB, 256, 0, stream>>>(B1, dW2, nullptr, B2, NNODES, 128, 256, 1);
    // A4 = agg(H4) + db2, emitted directly as bf16 hi/lo split -> Ah/Al (in B1)
    k_spmm_split<<<(NNODES * 32 + 255) / 256, 256, 0, stream>>>(B2, dinv, rowptr, col, val, db2, Ah, Al);
    // x_hat = (Ah+Al) @ (Wh+Wl) + dbf -> d_out  [50000,1024]  via bf16 MFMA
    k_gemm_mfma_k128<<<MB * 8, 256, 0, stream>>>(Ah, Al, Whp, Wlp, dbf, out, NNODES, 1024);
}

// Round 3
// 726.891 us; speedup vs baseline: 1.3530x; 1.1603x over previous
//
#include <hip/hip_runtime.h>
#include <math.h>

#define NNODES 50000
#define NEDGES 800000

typedef float v4f __attribute__((ext_vector_type(4)));
typedef short bf16x8 __attribute__((ext_vector_type(8)));
typedef float f32x4 __attribute__((ext_vector_type(4)));
typedef unsigned short u16x4 __attribute__((ext_vector_type(4)));

// bf16 round-to-nearest-even helpers
__device__ __forceinline__ unsigned short f2bf(float f) {
    unsigned u = __float_as_uint(f);
    return (unsigned short)((u + 0x7fff + ((u >> 16) & 1)) >> 16);
}
__device__ __forceinline__ float bf2f(unsigned short h) {
    return __uint_as_float(((unsigned)h) << 16);
}

// ---------------- CSR build ----------------

__global__ void k_init_cnt(int* __restrict__ cnt) {
    int i = blockIdx.x * 256 + threadIdx.x;
    if (i < NNODES) cnt[i] = 0;
}

__global__ void k_count(const int* __restrict__ dst, int* __restrict__ cnt) {
    int e = blockIdx.x * 256 + threadIdx.x;
    if (e < NEDGES) atomicAdd(&cnt[dst[e]], 1);
}

__global__ void k_dinv(const int* __restrict__ cnt, float* __restrict__ dinv) {
    int i = blockIdx.x * 256 + threadIdx.x;
    if (i < NNODES) dinv[i] = 1.0f / sqrtf((float)cnt[i] + 1.0f);  // +1 self loop
}

// ---- hierarchical exclusive scan of cnt -> rowptr (3 passes, all parallel) ----
// Replaces the single-block k_scan (125 us: 1 CU, uncoalesced, latency-bound).

// pass 1: per-block (256-elem) sums
__global__ __launch_bounds__(256) void k_bsum(const int* __restrict__ cnt,
                                              int* __restrict__ bsum) {
    __shared__ int red[256];
    int i = blockIdx.x * 256 + threadIdx.x;
    int t = threadIdx.x;
    red[t] = (i < NNODES) ? cnt[i] : 0;
    __syncthreads();
#pragma unroll
    for (int off = 128; off > 0; off >>= 1) {
        if (t < off) red[t] += red[t + off];
        __syncthreads();
    }
    if (t == 0) bsum[blockIdx.x] = red[0];
}

// pass 2: single-block exclusive scan of the block sums (nblk <= 256)
__global__ __launch_bounds__(256) void k_bscan(int* __restrict__ bsum, int nblk) {
    __shared__ int s[256];
    int t = threadIdx.x;
    int v = (t < nblk) ? bsum[t] : 0;
    s[t] = v;
    __syncthreads();
#pragma unroll
    for (int off = 1; off < 256; off <<= 1) {
        int u = 0;
        if (t >= off) u = s[t - off];
        __syncthreads();
        if (t >= off) s[t] += u;
        __syncthreads();
    }
    if (t < nblk) bsum[t] = s[t] - v;   // exclusive base
}

// pass 3: in-block exclusive scan + block base -> rowptr; zero cnt (cursor reuse)
__global__ __launch_bounds__(256) void k_rowptr(int* __restrict__ cnt,
                                                const int* __restrict__ bsum,
                                                int* __restrict__ rowptr) {
    __shared__ int s[256];
    int i = blockIdx.x * 256 + threadIdx.x;
    int t = threadIdx.x;
    int v = (i < NNODES) ? cnt[i] : 0;
    s[t] = v;
    __syncthreads();
#pragma unroll
    for (int off = 1; off < 256; off <<= 1) {
        int u = 0;
        if (t >= off) u = s[t - off];
        __syncthreads();
        if (t >= off) s[t] += u;
        __syncthreads();
    }
    if (i < NNODES) {
        rowptr[i] = bsum[blockIdx.x] + s[t] - v;   // exclusive
        cnt[i] = 0;
    }
    if (i == 0) rowptr[NNODES] = NEDGES;           // total == E by construction
}

__global__ void k_fill(const int* __restrict__ src, const int* __restrict__ dst,
                       const int* __restrict__ rowptr, int* __restrict__ cursor,
                       const float* __restrict__ dinv,
                       int* __restrict__ col, float* __restrict__ val) {
    int e = blockIdx.x * 256 + threadIdx.x;
    if (e < NEDGES) {
        int s = src[e], d = dst[e];
        int pos = rowptr[d] + atomicAdd(&cursor[d], 1);
        col[pos] = s;
        val[pos] = dinv[s] * dinv[d];
    }
}

// ---------------- W split+permute for MFMA B-fragments ----------------
// W[128][1024] fp32 -> Wh/Wl bf16 in fragment order:
// slot (kt, nt, lane, j) holds W[kt*32 + (lane>>4)*8 + j][nt*16 + (lane&15)]
// so the GEMM's B-frag is ONE coalesced 16B load per lane.

__global__ void k_wsplit(const float* __restrict__ W, unsigned short* __restrict__ Wh,
                         unsigned short* __restrict__ Wl) {
    int idx = blockIdx.x * 256 + threadIdx.x;
    if (idx >= 128 * 1024) return;
    int k = idx >> 10;          // 0..127
    int n = idx & 1023;
    float a = W[idx];
    unsigned short h = f2bf(a);
    unsigned short l = f2bf(a - bf2f(h));
    int kt = k >> 5, kr = k & 31;
    int g = kr >> 3, j = kr & 7;
    int nt = n >> 4, nc = n & 15;
    int lane = g * 16 + nc;
    size_t off = ((size_t)(kt * 64 + nt) * 64 + lane) * 8 + j;
    Wh[off] = h;
    Wl[off] = l;
}

// ---------------- fp32 tiled GEMM (unchanged core) ----------------

template<int BM, int BN, int BK, int TM, int TN, bool NT, bool RELU>
__global__ __launch_bounds__(256) void k_gemm(const float* __restrict__ A,
                                              const float* __restrict__ W,
                                              const float* __restrict__ bias,
                                              float* __restrict__ C,
                                              int M, int Ncols, int K, int NB) {
    __shared__ __align__(16) float As[BK][BM];   // transposed A tile
    __shared__ __align__(16) float Ws[BK][BN];

    constexpr int CHN = TN / 4;        // float4 chunks per thread (cols)
    constexpr int SN  = BN / CHN;      // column stride between chunks
    constexpr int NTX = SN / 4;        // thread-columns

    const int tid = threadIdx.x;
    const int tx = tid % NTX;
    const int ty = tid / NTX;
    const int bid = blockIdx.x;
    const int m0 = (bid / NB) * BM;
    const int n0 = (bid % NB) * BN;

    float acc[TM][TN];
#pragma unroll
    for (int i = 0; i < TM; ++i)
#pragma unroll
        for (int j = 0; j < TN; ++j) acc[i][j] = 0.0f;

    constexpr int AITER = (BM * BK / 4) / 256;
    constexpr int WITER = (BK * BN / 4) / 256;

    for (int k0 = 0; k0 < K; k0 += BK) {
#pragma unroll
        for (int it = 0; it < AITER; ++it) {
            int f4 = tid + it * 256;
            int row = f4 / (BK / 4);
            int kk = (f4 % (BK / 4)) * 4;
            float4 v = make_float4(0.f, 0.f, 0.f, 0.f);
            int gr = m0 + row;
            if (gr < M) v = *(const float4*)&A[(size_t)gr * K + k0 + kk];
            As[kk + 0][row] = v.x;
            As[kk + 1][row] = v.y;
            As[kk + 2][row] = v.z;
            As[kk + 3][row] = v.w;
        }
#pragma unroll
        for (int it = 0; it < WITER; ++it) {
            int f4 = tid + it * 256;
            int kk = f4 / (BN / 4);
            int nn = (f4 % (BN / 4)) * 4;
            *(float4*)&Ws[kk][nn] = *(const float4*)&W[(size_t)(k0 + kk) * Ncols + n0 + nn];
        }
        __syncthreads();

#pragma unroll
        for (int kk = 0; kk < BK; ++kk) {
            float a[TM], b[TN];
#pragma unroll
            for (int i = 0; i < TM; i += 4)
                *(float4*)&a[i] = *(const float4*)&As[kk][ty * TM + i];
#pragma unroll
            for (int c = 0; c < CHN; ++c)
                *(float4*)&b[c * 4] = *(const float4*)&Ws[kk][c * SN + tx * 4];
#pragma unroll
            for (int i = 0; i < TM; ++i)
#pragma unroll
                for (int j = 0; j < TN; ++j)
                    acc[i][j] = fmaf(a[i], b[j], acc[i][j]);
        }
        __syncthreads();
    }

#pragma unroll
    for (int i = 0; i < TM; ++i) {
        int gr = m0 + ty * TM + i;
        if (gr < M) {
#pragma unroll
            for (int c = 0; c < CHN; ++c) {
                int nb = n0 + c * SN + tx * 4;
                float4 v;
                v.x = acc[i][c * 4 + 0];
                v.y = acc[i][c * 4 + 1];
                v.z = acc[i][c * 4 + 2];
                v.w = acc[i][c * 4 + 3];
                if (bias != nullptr) {
                    v.x += bias[nb + 0];
                    v.y += bias[nb + 1];
                    v.z += bias[nb + 2];
                    v.w += bias[nb + 3];
                }
                if (RELU) {
                    v.x = fmaxf(v.x, 0.f);
                    v.y = fmaxf(v.y, 0.f);
                    v.z = fmaxf(v.z, 0.f);
                    v.w = fmaxf(v.w, 0.f);
                }
                if (NT) {
                    v4f nv;
                    nv.x = v.x; nv.y = v.y; nv.z = v.z; nv.w = v.w;
                    __builtin_nontemporal_store(nv, (v4f*)&C[(size_t)gr * Ncols + nb]);
                } else {
                    *(float4*)&C[(size_t)gr * Ncols + nb] = v;
                }
            }
        }
    }
}

// ---------------- MFMA bf16-split GEMM for the final layer ----------------
// C[M,1024] = (Ah+Al)[M,128] @ (Wh+Wl)[128,1024] + bias, fp32 accumulate.
// 3-product split: Ah*Wh + Ah*Wl + Al*Wh (Al*Wl ~2^-18, dropped).
// No LDS: A-frags are contiguous 16B loads from row-major bf16; W is
// pre-permuted (k_wsplit) into exact B-fragment order and stays L2-hot.
// Block=256 (4 waves, 2x2), tile 128x128, per-wave 64x64 = 4x4 16x16 frags.

__global__ __launch_bounds__(256) void k_gemm_mfma_k128(
        const unsigned short* __restrict__ Ah, const unsigned short* __restrict__ Al,
        const unsigned short* __restrict__ Wh, const unsigned short* __restrict__ Wl,
        const float* __restrict__ bias, float* __restrict__ C, int M, int Ncols) {
    const int lane = threadIdx.x & 63;
    const int wave = threadIdx.x >> 6;
    const int wr = wave >> 1, wc = wave & 1;
    const int l15 = lane & 15, l4 = lane >> 4;
    const int bid = blockIdx.x;
    const int NB = Ncols >> 7;                // n-fastest: A-tile reuse in L2
    const int m0 = (bid / NB) * 128;
    const int n0 = (bid % NB) * 128;

    f32x4 acc[4][4];
#pragma unroll
    for (int i = 0; i < 4; ++i)
#pragma unroll
        for (int j = 0; j < 4; ++j) {
            f32x4 z = {0.f, 0.f, 0.f, 0.f};
            acc[i][j] = z;
        }

    int arow[4];
#pragma unroll
    for (int mf = 0; mf < 4; ++mf) {
        int r = m0 + wr * 64 + mf * 16 + l15;
        arow[mf] = r < M ? r : M - 1;         // clamp: OOB rows never stored
    }
    const int ntbase = (n0 + wc * 64) >> 4;

#pragma unroll
    for (int kt = 0; kt < 4; ++kt) {
        bf16x8 ah[4], al[4], bh[4], bl[4];
        const int ka = kt * 32 + l4 * 8;
#pragma unroll
        for (int mf = 0; mf < 4; ++mf) {
            ah[mf] = *(const bf16x8*)&Ah[(size_t)arow[mf] * 128 + ka];
            al[mf] = *(const bf16x8*)&Al[(size_t)arow[mf] * 128 + ka];
        }
#pragma unroll
        for (int nf = 0; nf < 4; ++nf) {
            size_t off = ((size_t)(kt * 64 + ntbase + nf) * 64 + lane) * 8;
            bh[nf] = *(const bf16x8*)&Wh[off];
            bl[nf] = *(const bf16x8*)&Wl[off];
        }
#pragma unroll
        for (int mf = 0; mf < 4; ++mf)
#pragma unroll
            for (int nf = 0; nf < 4; ++nf) {
                acc[mf][nf] = __builtin_amdgcn_mfma_f32_16x16x32_bf16(ah[mf], bh[nf], acc[mf][nf], 0, 0, 0);
                acc[mf][nf] = __builtin_amdgcn_mfma_f32_16x16x32_bf16(ah[mf], bl[nf], acc[mf][nf], 0, 0, 0);
                acc[mf][nf] = __builtin_amdgcn_mfma_f32_16x16x32_bf16(al[mf], bh[nf], acc[mf][nf], 0, 0, 0);
            }
    }

    float bv[4];
#pragma unroll
    for (int nf = 0; nf < 4; ++nf) bv[nf] = bias[n0 + wc * 64 + nf * 16 + l15];

    // C/D layout (m89-verified): col = lane&15, row = (lane>>4)*4 + reg
#pragma unroll
    for (int mf = 0; mf < 4; ++mf) {
        int gr0 = m0 + wr * 64 + mf * 16 + l4 * 4;
#pragma unroll
        for (int r = 0; r < 4; ++r) {
            int gr = gr0 + r;
            if (gr < M) {
#pragma unroll
                for (int nf = 0; nf < 4; ++nf) {
                    float v = acc[mf][nf][r] + bv[nf];
                    __builtin_nontemporal_store(v, &C[(size_t)gr * Ncols + n0 + wc * 64 + nf * 16 + l15]);
                }
            }
        }
    }
}

// ---------------- CSR SpMM (aggregation + self loop + optional bias/relu) ----

template<int CH, bool RELU, bool HB>
__global__ __launch_bounds__(256) void k_spmm(const float* __restrict__ H,
                                              const float* __restrict__ dinv,
                                              const int* __restrict__ rowptr,
                                              const int* __restrict__ col,
                                              const float* __restrict__ val,
                                              const float* __restrict__ bias,
                                              float* __restrict__ out) {
    constexpr int CV = CH / 4;
    int t = blockIdx.x * 256 + threadIdx.x;
    int row = t / CV;
    if (row >= NNODES) return;
    int c = (t % CV) * 4;

    float dv = dinv[row];
    float s2 = dv * dv;
    float4 h = *(const float4*)&H[(size_t)row * CH + c];
    float ax, ay, az, aw;
    if (HB) {
        float4 b = *(const float4*)&bias[c];
        ax = fmaf(h.x, s2, b.x);
        ay = fmaf(h.y, s2, b.y);
        az = fmaf(h.z, s2, b.z);
        aw = fmaf(h.w, s2, b.w);
    } else {
        ax = h.x * s2;
        ay = h.y * s2;
        az = h.z * s2;
        aw = h.w * s2;
    }

    const int e0 = rowptr[row], e1 = rowptr[row + 1];
    int e = e0;
    for (; e + 8 <= e1; e += 8) {
        int s[8];
        float w[8];
#pragma unroll
        for (int u = 0; u < 8; ++u) { s[u] = col[e + u]; w[u] = val[e + u]; }
        float4 hv[8];
#pragma unroll
        for (int u = 0; u < 8; ++u)
            hv[u] = *(const float4*)&H[(size_t)s[u] * CH + c];
#pragma unroll
        for (int u = 0; u < 8; ++u) {
            ax = fmaf(hv[u].x, w[u], ax);
            ay = fmaf(hv[u].y, w[u], ay);
            az = fmaf(hv[u].z, w[u], az);
            aw = fmaf(hv[u].w, w[u], aw);
        }
    }
    for (; e < e1; ++e) {
        int sidx = col[e];
        float w = val[e];
        float4 hv = *(const float4*)&H[(size_t)sidx * CH + c];
        ax = fmaf(hv.x, w, ax);
        ay = fmaf(hv.y, w, ay);
        az = fmaf(hv.z, w, az);
        aw = fmaf(hv.w, w, aw);
    }
    if (RELU) {
        ax = fmaxf(ax, 0.f);
        ay = fmaxf(ay, 0.f);
        az = fmaxf(az, 0.f);
        aw = fmaxf(aw, 0.f);
    }
    float4 o;
    o.x = ax; o.y = ay; o.z = az; o.w = aw;
    *(float4*)&out[(size_t)row * CH + c] = o;
}

// ---- SpMM variant for A4 (CH=128, bias, no relu) that writes the bf16
// hi/lo split directly (feeds the MFMA final GEMM; fp32 A4 never hits HBM).

__global__ __launch_bounds__(256) void k_spmm_split(const float* __restrict__ H,
                                                    const float* __restrict__ dinv,
                                                    const int* __restrict__ rowptr,
                                                    const int* __restrict__ col,
                                                    const float* __restrict__ val,
                                                    const float* __restrict__ bias,
                                                    unsigned short* __restrict__ Ah,
                                                    unsigned short* __restrict__ Al) {
    int t = blockIdx.x * 256 + threadIdx.x;
    int row = t / 32;
    if (row >= NNODES) return;
    int c = (t % 32) * 4;

    float dv = dinv[row];
    float s2 = dv * dv;
    float4 h = *(const float4*)&H[(size_t)row * 128 + c];
    float4 b = *(const float4*)&bias[c];
    float ax = fmaf(h.x, s2, b.x);
    float ay = fmaf(h.y, s2, b.y);
    float az = fmaf(h.z, s2, b.z);
    float aw = fmaf(h.w, s2, b.w);

    const int e0 = rowptr[row], e1 = rowptr[row + 1];
    int e = e0;
    for (; e + 8 <= e1; e += 8) {
        int s[8];
        float w[8];
#pragma unroll
        for (int u = 0; u < 8; ++u) { s[u] = col[e + u]; w[u] = val[e + u]; }
        float4 hv[8];
#pragma unroll
        for (int u = 0; u < 8; ++u)
            hv[u] = *(const float4*)&H[(size_t)s[u] * 128 + c];
#pragma unroll
        for (int u = 0; u < 8; ++u) {
            ax = fmaf(hv[u].x, w[u], ax);
            ay = fmaf(hv[u].y, w[u], ay);
            az = fmaf(hv[u].z, w[u], az);
            aw = fmaf(hv[u].w, w[u], aw);
        }
    }
    for (; e < e1; ++e) {
        int sidx = col[e];
        float w = val[e];
        float4 hv = *(const float4*)&H[(size_t)sidx * 128 + c];
        ax = fmaf(hv.x, w, ax);
        ay = fmaf(hv.y, w, ay);
        az = fmaf(hv.z, w, az);
        aw = fmaf(hv.w, w, aw);
    }

    u16x4 hvv, lvv;
    hvv.x = f2bf(ax); lvv.x = f2bf(ax - bf2f(hvv.x));
    hvv.y = f2bf(ay); lvv.y = f2bf(ay - bf2f(hvv.y));
    hvv.z = f2bf(az); lvv.z = f2bf(az - bf2f(hvv.z));
    hvv.w = f2bf(aw); lvv.w = f2bf(aw - bf2f(hvv.w));
    *(u16x4*)&Ah[(size_t)row * 128 + c] = hvv;
    *(u16x4*)&Al[(size_t)row * 128 + c] = lvv;
}

// ---------------- launcher ----------------

extern "C" void kernel_launch(void* const* d_in, const int* in_sizes, int n_in,
                              void* d_out, int out_size, void* d_ws, size_t ws_size,
                              hipStream_t stream) {
    const float* x   = (const float*)d_in[0];
    const int*   ei  = (const int*)d_in[1];
    const float* eW1 = (const float*)d_in[2];
    const float* eb1 = (const float*)d_in[3];
    const float* eW2 = (const float*)d_in[4];
    const float* eb2 = (const float*)d_in[5];
    const float* eWf = (const float*)d_in[6];
    const float* ebf = (const float*)d_in[7];
    const float* dW1 = (const float*)d_in[8];
    const float* db1 = (const float*)d_in[9];
    const float* dW2 = (const float*)d_in[10];
    const float* db2 = (const float*)d_in[11];
    const float* dWf = (const float*)d_in[12];
    const float* dbf = (const float*)d_in[13];
    float* out = (float*)d_out;

    char* ws = (char*)d_ws;
    size_t off = 0;
    auto alloc = [&](size_t bytes) { size_t r = off; off += (bytes + 255) & ~(size_t)255; return r; };
    float* dinv   = (float*)(ws + alloc((size_t)NNODES * 4));
    int*   cnt    = (int*)  (ws + alloc((size_t)NNODES * 4));
    int*   rowptr = (int*)  (ws + alloc((size_t)(NNODES + 1) * 4));
    int*   bsum   = (int*)  (ws + alloc((size_t)256 * 4));
    int*   col    = (int*)  (ws + alloc((size_t)NEDGES * 4));
    float* val    = (float*)(ws + alloc((size_t)NEDGES * 4));
    float* B1     = (float*)(ws + alloc((size_t)NNODES * 256 * 4));
    unsigned short* Whp = (unsigned short*)(ws + alloc((size_t)128 * 1024 * 2));
    unsigned short* Wlp = (unsigned short*)(ws + alloc((size_t)128 * 1024 * 2));
    // Ah/Al (bf16 split of A4, 12.8 MB each) alias B1: A3 (which filled B1)
    // is dead once H4 is computed, and the A4-spmm writes only these.
    unsigned short* Ah = (unsigned short*)B1;
    unsigned short* Al = (unsigned short*)((char*)B1 + (size_t)NNODES * 128 * 2);
    // B2 aliases the front of d_out (204.8 MB total; B2 needs <=51.2 MB).
    float* B2 = out;

    const int* src = ei;
    const int* dst = ei + NEDGES;

    const int gN = (NNODES + 255) / 256;   // 196
    const int gE = (NEDGES + 255) / 256;

    k_init_cnt<<<gN, 256, 0, stream>>>(cnt);
    k_count<<<gE, 256, 0, stream>>>(dst, cnt);
    k_dinv<<<gN, 256, 0, stream>>>(cnt, dinv);
    k_bsum<<<gN, 256, 0, stream>>>(cnt, bsum);
    k_bscan<<<1, 256, 0, stream>>>(bsum, gN);
    k_rowptr<<<gN, 256, 0, stream>>>(cnt, bsum, rowptr);
    k_fill<<<gE, 256, 0, stream>>>(src, dst, rowptr, cnt, dinv, col, val);
    // W split+permute for the final GEMM (no pipeline deps; 512 KB)
    k_wsplit<<<(128 * 1024 + 255) / 256, 256, 0, stream>>>(dWf, Whp, Wlp);

    const int MB = (NNODES + 127) / 128;   // 391 row-blocks

    // Encoder:
    // H1 = x @ eW1  [50000,128]x[128,128] -> B1
    k_gemm<128,128,16,8,8,false,false><<<MB, 256, 0, stream>>>(x, eW1, nullptr, B1, NNODES, 128, 128, 1);
    // A1 = relu(agg(H1) + eb1) -> B2   (agg at 128 ch)
    k_spmm<128,true,true><<<(NNODES * 32 + 255) / 256, 256, 0, stream>>>(B1, dinv, rowptr, col, val, eb1, B2);
    // H2 = A1 @ eW2  [128->64] -> B1
    k_gemm<128,64,16,8,4,false,false><<<MB, 256, 0, stream>>>(B2, eW2, nullptr, B1, NNODES, 64, 128, 1);
    // A2 = agg(H2) + eb2 -> B2         (agg at 64 ch)
    k_spmm<64,false,true><<<(NNODES * 16 + 255) / 256, 256, 0, stream>>>(B1, dinv, rowptr, col, val, eb2, B2);
    // Z = A2 @ eWf + ebf -> B1  [50000,64]
    k_gemm<128,64,16,8,4,false,false><<<MB, 256, 0, stream>>>(B2, eWf, ebf, B1, NNODES, 64, 64, 1);

    // Decoder layer 1 (reassociated): relu(agg(Z) @ dW1 + db1)
    // G = agg(Z) -> B2                 (agg at 64 ch, NO bias)
    k_spmm<64,false,false><<<(NNODES * 16 + 255) / 256, 256, 0, stream>>>(B1, dinv, rowptr, col, val, nullptr, B2);
    // A3 = relu(G @ dW1 + db1) -> B1  [50000,256]  (bias+relu fused)
    k_gemm<128,128,16,8,8,false,true><<<MB * 2, 256, 0, stream>>>(B2, dW1, db1, B1, NNODES, 256, 64, 2);

    // Decoder layer 2:
    // H4 = A3 @ dW2  [256->128] -> B2
    k_gemm<128,128,16,8,8,false,false><<<MB, 256, 0, stream>>>(B1, dW2, nullptr, B2, NNODES, 128, 256, 1);
    // A4 = agg(H4) + db2, emitted directly as bf16 hi/lo split -> Ah/Al (in B1)
    k_spmm_split<<<(NNODES * 32 + 255) / 256, 256, 0, stream>>>(B2, dinv, rowptr, col, val, db2, Ah, Al);
    // x_hat = (Ah+Al) @ (Wh+Wl) + dbf -> d_out  [50000,1024]  via bf16 MFMA
    k_gemm_mfma_k128<<<MB * 8, 256, 0, stream>>>(Ah, Al, Whp, Wlp, dbf, out, NNODES, 1024);
}

// Round 4
// 699.648 us; speedup vs baseline: 1.4057x; 1.0389x over previous
//
#include <hip/hip_runtime.h>
#include <math.h>

#define NNODES 50000
#define NEDGES 800000

typedef float v4f __attribute__((ext_vector_type(4)));
typedef short bf16x8 __attribute__((ext_vector_type(8)));
typedef float f32x4 __attribute__((ext_vector_type(4)));
typedef unsigned short u16x4 __attribute__((ext_vector_type(4)));

// bf16 round-to-nearest-even helpers
__device__ __forceinline__ unsigned short f2bf(float f) {
    unsigned u = __float_as_uint(f);
    return (unsigned short)((u + 0x7fff + ((u >> 16) & 1)) >> 16);
}
__device__ __forceinline__ float bf2f(unsigned short h) {
    return __uint_as_float(((unsigned)h) << 16);
}

// ---------------- CSR build ----------------

__global__ void k_init_cnt(int* __restrict__ cnt) {
    int i = blockIdx.x * 256 + threadIdx.x;
    if (i < NNODES) cnt[i] = 0;
}

__global__ void k_count(const int* __restrict__ dst, int* __restrict__ cnt) {
    int e = blockIdx.x * 256 + threadIdx.x;
    if (e < NEDGES) atomicAdd(&cnt[dst[e]], 1);
}

__global__ void k_dinv(const int* __restrict__ cnt, float* __restrict__ dinv) {
    int i = blockIdx.x * 256 + threadIdx.x;
    if (i < NNODES) dinv[i] = 1.0f / sqrtf((float)cnt[i] + 1.0f);  // +1 self loop
}

// ---- hierarchical exclusive scan of cnt -> rowptr (3 passes, all parallel) ----

__global__ __launch_bounds__(256) void k_bsum(const int* __restrict__ cnt,
                                              int* __restrict__ bsum) {
    __shared__ int red[256];
    int i = blockIdx.x * 256 + threadIdx.x;
    int t = threadIdx.x;
    red[t] = (i < NNODES) ? cnt[i] : 0;
    __syncthreads();
#pragma unroll
    for (int off = 128; off > 0; off >>= 1) {
        if (t < off) red[t] += red[t + off];
        __syncthreads();
    }
    if (t == 0) bsum[blockIdx.x] = red[0];
}

__global__ __launch_bounds__(256) void k_bscan(int* __restrict__ bsum, int nblk) {
    __shared__ int s[256];
    int t = threadIdx.x;
    int v = (t < nblk) ? bsum[t] : 0;
    s[t] = v;
    __syncthreads();
#pragma unroll
    for (int off = 1; off < 256; off <<= 1) {
        int u = 0;
        if (t >= off) u = s[t - off];
        __syncthreads();
        if (t >= off) s[t] += u;
        __syncthreads();
    }
    if (t < nblk) bsum[t] = s[t] - v;   // exclusive base
}

__global__ __launch_bounds__(256) void k_rowptr(int* __restrict__ cnt,
                                                const int* __restrict__ bsum,
                                                int* __restrict__ rowptr) {
    __shared__ int s[256];
    int i = blockIdx.x * 256 + threadIdx.x;
    int t = threadIdx.x;
    int v = (i < NNODES) ? cnt[i] : 0;
    s[t] = v;
    __syncthreads();
#pragma unroll
    for (int off = 1; off < 256; off <<= 1) {
        int u = 0;
        if (t >= off) u = s[t - off];
        __syncthreads();
        if (t >= off) s[t] += u;
        __syncthreads();
    }
    if (i < NNODES) {
        rowptr[i] = bsum[blockIdx.x] + s[t] - v;   // exclusive
        cnt[i] = 0;
    }
    if (i == 0) rowptr[NNODES] = NEDGES;
}

__global__ void k_fill(const int* __restrict__ src, const int* __restrict__ dst,
                       const int* __restrict__ rowptr, int* __restrict__ cursor,
                       const float* __restrict__ dinv,
                       int* __restrict__ col, float* __restrict__ val) {
    int e = blockIdx.x * 256 + threadIdx.x;
    if (e < NEDGES) {
        int s = src[e], d = dst[e];
        int pos = rowptr[d] + atomicAdd(&cursor[d], 1);
        col[pos] = s;
        val[pos] = dinv[s] * dinv[d];
    }
}

// ---------------- W split+permute for MFMA B-fragments (generalized) ---------
// W[K][N] fp32 -> Wh/Wl bf16 in fragment order:
// slot (kt, nt, lane, j) holds W[kt*32 + (lane>>4)*8 + j][nt*16 + (lane&15)]
// so a B-frag is ONE coalesced 16B load per lane.

__global__ void k_wsplit(const float* __restrict__ W, unsigned short* __restrict__ Wh,
                         unsigned short* __restrict__ Wl, int K, int N) {
    int idx = blockIdx.x * 256 + threadIdx.x;
    if (idx >= K * N) return;
    int k = idx / N;
    int n = idx - k * N;
    float a = W[idx];
    unsigned short h = f2bf(a);
    unsigned short l = f2bf(a - bf2f(h));
    int kt = k >> 5, kr = k & 31;
    int g = kr >> 3, j = kr & 7;
    int nt = n >> 4, nc = n & 15;
    int lane = g * 16 + nc;
    size_t off = ((size_t)(kt * (N >> 4) + nt) * 64 + lane) * 8 + j;
    Wh[off] = h;
    Wl[off] = l;
}

// ---------------- fp32 tiled GEMM (encoder only) ----------------

template<int BM, int BN, int BK, int TM, int TN, bool NT, bool RELU>
__global__ __launch_bounds__(256) void k_gemm(const float* __restrict__ A,
                                              const float* __restrict__ W,
                                              const float* __restrict__ bias,
                                              float* __restrict__ C,
                                              int M, int Ncols, int K, int NB) {
    __shared__ __align__(16) float As[BK][BM];   // transposed A tile
    __shared__ __align__(16) float Ws[BK][BN];

    constexpr int CHN = TN / 4;
    constexpr int SN  = BN / CHN;
    constexpr int NTX = SN / 4;

    const int tid = threadIdx.x;
    const int tx = tid % NTX;
    const int ty = tid / NTX;
    const int bid = blockIdx.x;
    const int m0 = (bid / NB) * BM;
    const int n0 = (bid % NB) * BN;

    float acc[TM][TN];
#pragma unroll
    for (int i = 0; i < TM; ++i)
#pragma unroll
        for (int j = 0; j < TN; ++j) acc[i][j] = 0.0f;

    constexpr int AITER = (BM * BK / 4) / 256;
    constexpr int WITER = (BK * BN / 4) / 256;

    for (int k0 = 0; k0 < K; k0 += BK) {
#pragma unroll
        for (int it = 0; it < AITER; ++it) {
            int f4 = tid + it * 256;
            int row = f4 / (BK / 4);
            int kk = (f4 % (BK / 4)) * 4;
            float4 v = make_float4(0.f, 0.f, 0.f, 0.f);
            int gr = m0 + row;
            if (gr < M) v = *(const float4*)&A[(size_t)gr * K + k0 + kk];
            As[kk + 0][row] = v.x;
            As[kk + 1][row] = v.y;
            As[kk + 2][row] = v.z;
            As[kk + 3][row] = v.w;
        }
#pragma unroll
        for (int it = 0; it < WITER; ++it) {
            int f4 = tid + it * 256;
            int kk = f4 / (BN / 4);
            int nn = (f4 % (BN / 4)) * 4;
            *(float4*)&Ws[kk][nn] = *(const float4*)&W[(size_t)(k0 + kk) * Ncols + n0 + nn];
        }
        __syncthreads();

#pragma unroll
        for (int kk = 0; kk < BK; ++kk) {
            float a[TM], b[TN];
#pragma unroll
            for (int i = 0; i < TM; i += 4)
                *(float4*)&a[i] = *(const float4*)&As[kk][ty * TM + i];
#pragma unroll
            for (int c = 0; c < CHN; ++c)
                *(float4*)&b[c * 4] = *(const float4*)&Ws[kk][c * SN + tx * 4];
#pragma unroll
            for (int i = 0; i < TM; ++i)
#pragma unroll
                for (int j = 0; j < TN; ++j)
                    acc[i][j] = fmaf(a[i], b[j], acc[i][j]);
        }
        __syncthreads();
    }

#pragma unroll
    for (int i = 0; i < TM; ++i) {
        int gr = m0 + ty * TM + i;
        if (gr < M) {
#pragma unroll
            for (int c = 0; c < CHN; ++c) {
                int nb = n0 + c * SN + tx * 4;
                float4 v;
                v.x = acc[i][c * 4 + 0];
                v.y = acc[i][c * 4 + 1];
                v.z = acc[i][c * 4 + 2];
                v.w = acc[i][c * 4 + 3];
                if (bias != nullptr) {
                    v.x += bias[nb + 0];
                    v.y += bias[nb + 1];
                    v.z += bias[nb + 2];
                    v.w += bias[nb + 3];
                }
                if (RELU) {
                    v.x = fmaxf(v.x, 0.f);
                    v.y = fmaxf(v.y, 0.f);
                    v.z = fmaxf(v.z, 0.f);
                    v.w = fmaxf(v.w, 0.f);
                }
                if (NT) {
                    v4f nv;
                    nv.x = v.x; nv.y = v.y; nv.z = v.z; nv.w = v.w;
                    __builtin_nontemporal_store(nv, (v4f*)&C[(size_t)gr * Ncols + nb]);
                } else {
                    *(float4*)&C[(size_t)gr * Ncols + nb] = v;
                }
            }
        }
    }
}

// ---------------- MFMA bf16-split GEMM (generalized over K) ----------------
// C[M,N] = (Ah+Al)[M,K] @ (Wh+Wl)[K,N] (+bias) (+relu), fp32 accumulate.
// 3-product split: Ah*Wh + Ah*Wl + Al*Wh (Al*Wl ~2^-34 rel, dropped).
// No LDS. A-frags: contiguous 16B loads from row-major bf16. W pre-permuted
// (k_wsplit) into exact B-fragment order, L2-hot.
// Block mapping is M-FASTEST: consecutive bids = consecutive m-blocks, same
// n-block. XCD round-robin then gives each A row-block to exactly one XCD
// (A fetched once chip-wide); B per n-block is tiny (<=128KB) and L2-hot.
// (n-fastest was the round-2 bug: 8 consecutive bids = 8 XCDs re-fetching
// the same A rows through private L2s -> ~8x A over-fetch.)
// SPLIT: emit bf16 hi/lo C (feeds a downstream MFMA GEMM) instead of fp32.

template<int K, bool RELU, bool SPLIT, bool NT>
__global__ __launch_bounds__(256) void k_mfma(
        const unsigned short* __restrict__ Ah, const unsigned short* __restrict__ Al,
        const unsigned short* __restrict__ Wh, const unsigned short* __restrict__ Wl,
        const float* __restrict__ bias, float* __restrict__ C,
        unsigned short* __restrict__ Ch, unsigned short* __restrict__ Cl,
        int M, int Ncols) {
    constexpr int KT = K / 32;
    const int lane = threadIdx.x & 63;
    const int wave = threadIdx.x >> 6;
    const int wr = wave >> 1, wc = wave & 1;
    const int l15 = lane & 15, l4 = lane >> 4;
    const int bid = blockIdx.x;
    const int MBLK = (M + 127) >> 7;
    const int m0 = (bid % MBLK) * 128;        // m-fastest
    const int n0 = (bid / MBLK) * 128;
    const int NT16 = Ncols >> 4;

    f32x4 acc[4][4];
#pragma unroll
    for (int i = 0; i < 4; ++i)
#pragma unroll
        for (int j = 0; j < 4; ++j) {
            f32x4 z = {0.f, 0.f, 0.f, 0.f};
            acc[i][j] = z;
        }

    int arow[4];
#pragma unroll
    for (int mf = 0; mf < 4; ++mf) {
        int r = m0 + wr * 64 + mf * 16 + l15;
        arow[mf] = r < M ? r : M - 1;         // clamp: OOB rows never stored
    }
    const int ntbase = (n0 + wc * 64) >> 4;

#pragma unroll
    for (int kt = 0; kt < KT; ++kt) {
        bf16x8 ah[4], al[4], bh[4], bl[4];
        const int ka = kt * 32 + l4 * 8;
#pragma unroll
        for (int mf = 0; mf < 4; ++mf) {
            ah[mf] = *(const bf16x8*)&Ah[(size_t)arow[mf] * K + ka];
            al[mf] = *(const bf16x8*)&Al[(size_t)arow[mf] * K + ka];
        }
#pragma unroll
        for (int nf = 0; nf < 4; ++nf) {
            size_t off = ((size_t)(kt * NT16 + ntbase + nf) * 64 + lane) * 8;
            bh[nf] = *(const bf16x8*)&Wh[off];
            bl[nf] = *(const bf16x8*)&Wl[off];
        }
#pragma unroll
        for (int mf = 0; mf < 4; ++mf)
#pragma unroll
            for (int nf = 0; nf < 4; ++nf) {
                acc[mf][nf] = __builtin_amdgcn_mfma_f32_16x16x32_bf16(ah[mf], bh[nf], acc[mf][nf], 0, 0, 0);
                acc[mf][nf] = __builtin_amdgcn_mfma_f32_16x16x32_bf16(ah[mf], bl[nf], acc[mf][nf], 0, 0, 0);
                acc[mf][nf] = __builtin_amdgcn_mfma_f32_16x16x32_bf16(al[mf], bh[nf], acc[mf][nf], 0, 0, 0);
            }
    }

    float bv[4];
#pragma unroll
    for (int nf = 0; nf < 4; ++nf)
        bv[nf] = bias ? bias[n0 + wc * 64 + nf * 16 + l15] : 0.0f;

    // C/D layout (m89-verified): col = lane&15, row = (lane>>4)*4 + reg
#pragma unroll
    for (int mf = 0; mf < 4; ++mf) {
        int gr0 = m0 + wr * 64 + mf * 16 + l4 * 4;
#pragma unroll
        for (int r = 0; r < 4; ++r) {
            int gr = gr0 + r;
            if (gr < M) {
#pragma unroll
                for (int nf = 0; nf < 4; ++nf) {
                    float v = acc[mf][nf][r] + bv[nf];
                    if (RELU) v = fmaxf(v, 0.f);
                    size_t ci = (size_t)gr * Ncols + n0 + wc * 64 + nf * 16 + l15;
                    if (SPLIT) {
                        unsigned short h = f2bf(v);
                        Ch[ci] = h;
                        Cl[ci] = f2bf(v - bf2f(h));
                    } else if (NT) {
                        __builtin_nontemporal_store(v, &C[ci]);
                    } else {
                        C[ci] = v;
                    }
                }
            }
        }
    }
}

// ---------------- CSR SpMM (aggregation + self loop) ----------------
// out[row] = sum_{e in row} H[col[e]] * val[e] + H[row]*dinv[row]^2 (+ bias)
// SPLIT: emit bf16 hi/lo (feeds a downstream MFMA GEMM) instead of fp32.

template<int CH, bool RELU, bool HB, bool SPLIT>
__global__ __launch_bounds__(256) void k_spmm(const float* __restrict__ H,
                                              const float* __restrict__ dinv,
                                              const int* __restrict__ rowptr,
                                              const int* __restrict__ col,
                                              const float* __restrict__ val,
                                              const float* __restrict__ bias,
                                              float* __restrict__ out,
                                              unsigned short* __restrict__ Oh,
                                              unsigned short* __restrict__ Ol) {
    constexpr int CV = CH / 4;
    int t = blockIdx.x * 256 + threadIdx.x;
    int row = t / CV;
    if (row >= NNODES) return;
    int c = (t % CV) * 4;

    float dv = dinv[row];
    float s2 = dv * dv;
    float4 h = *(const float4*)&H[(size_t)row * CH + c];
    float ax, ay, az, aw;
    if (HB) {
        float4 b = *(const float4*)&bias[c];
        ax = fmaf(h.x, s2, b.x);
        ay = fmaf(h.y, s2, b.y);
        az = fmaf(h.z, s2, b.z);
        aw = fmaf(h.w, s2, b.w);
    } else {
        ax = h.x * s2;
        ay = h.y * s2;
        az = h.z * s2;
        aw = h.w * s2;
    }

    const int e0 = rowptr[row], e1 = rowptr[row + 1];
    int e = e0;
    for (; e + 8 <= e1; e += 8) {
        int s[8];
        float w[8];
#pragma unroll
        for (int u = 0; u < 8; ++u) { s[u] = col[e + u]; w[u] = val[e + u]; }
        float4 hv[8];
#pragma unroll
        for (int u = 0; u < 8; ++u)
            hv[u] = *(const float4*)&H[(size_t)s[u] * CH + c];
#pragma unroll
        for (int u = 0; u < 8; ++u) {
            ax = fmaf(hv[u].x, w[u], ax);
            ay = fmaf(hv[u].y, w[u], ay);
            az = fmaf(hv[u].z, w[u], az);
            aw = fmaf(hv[u].w, w[u], aw);
        }
    }
    for (; e < e1; ++e) {
        int sidx = col[e];
        float w = val[e];
        float4 hv = *(const float4*)&H[(size_t)sidx * CH + c];
        ax = fmaf(hv.x, w, ax);
        ay = fmaf(hv.y, w, ay);
        az = fmaf(hv.z, w, az);
        aw = fmaf(hv.w, w, aw);
    }
    if (RELU) {
        ax = fmaxf(ax, 0.f);
        ay = fmaxf(ay, 0.f);
        az = fmaxf(az, 0.f);
        aw = fmaxf(aw, 0.f);
    }
    if (SPLIT) {
        u16x4 hvv, lvv;
        hvv.x = f2bf(ax); lvv.x = f2bf(ax - bf2f(hvv.x));
        hvv.y = f2bf(ay); lvv.y = f2bf(ay - bf2f(hvv.y));
        hvv.z = f2bf(az); lvv.z = f2bf(az - bf2f(hvv.z));
        hvv.w = f2bf(aw); lvv.w = f2bf(aw - bf2f(hvv.w));
        *(u16x4*)&Oh[(size_t)row * CH + c] = hvv;
        *(u16x4*)&Ol[(size_t)row * CH + c] = lvv;
    } else {
        float4 o;
        o.x = ax; o.y = ay; o.z = az; o.w = aw;
        *(float4*)&out[(size_t)row * CH + c] = o;
    }
}

// ---------------- launcher ----------------

extern "C" void kernel_launch(void* const* d_in, const int* in_sizes, int n_in,
                              void* d_out, int out_size, void* d_ws, size_t ws_size,
                              hipStream_t stream) {
    const float* x   = (const float*)d_in[0];
    const int*   ei  = (const int*)d_in[1];
    const float* eW1 = (const float*)d_in[2];
    const float* eb1 = (const float*)d_in[3];
    const float* eW2 = (const float*)d_in[4];
    const float* eb2 = (const float*)d_in[5];
    const float* eWf = (const float*)d_in[6];
    const float* ebf = (const float*)d_in[7];
    const float* dW1 = (const float*)d_in[8];
    const float* db1 = (const float*)d_in[9];
    const float* dW2 = (const float*)d_in[10];
    const float* db2 = (const float*)d_in[11];
    const float* dWf = (const float*)d_in[12];
    const float* dbf = (const float*)d_in[13];
    float* out = (float*)d_out;

    char* ws = (char*)d_ws;
    size_t off = 0;
    auto alloc = [&](size_t bytes) { size_t r = off; off += (bytes + 255) & ~(size_t)255; return r; };
    float* dinv   = (float*)(ws + alloc((size_t)NNODES * 4));
    int*   cnt    = (int*)  (ws + alloc((size_t)NNODES * 4));
    int*   rowptr = (int*)  (ws + alloc((size_t)(NNODES + 1) * 4));
    int*   bsum   = (int*)  (ws + alloc((size_t)256 * 4));
    int*   col    = (int*)  (ws + alloc((size_t)NEDGES * 4));
    float* val    = (float*)(ws + alloc((size_t)NEDGES * 4));
    float* B1     = (float*)(ws + alloc((size_t)NNODES * 256 * 4));
    unsigned short* Wfh = (unsigned short*)(ws + alloc((size_t)128 * 1024 * 2));  // dWf split
    unsigned short* Wfl = (unsigned short*)(ws + alloc((size_t)128 * 1024 * 2));
    unsigned short* W1h = (unsigned short*)(ws + alloc((size_t)64 * 256 * 2));    // dW1 split
    unsigned short* W1l = (unsigned short*)(ws + alloc((size_t)64 * 256 * 2));
    unsigned short* W2h = (unsigned short*)(ws + alloc((size_t)256 * 128 * 2));   // dW2 split
    unsigned short* W2l = (unsigned short*)(ws + alloc((size_t)256 * 128 * 2));

    // Aliases into B1 (51.2 MB) and B2 (= front of d_out, <=51.2 MB used):
    // timeline guarantees no overlap of live ranges (see per-call comments).
    float* B2 = out;
    unsigned short* Gh  = (unsigned short*)B2;                                    // agg(Z) split, 6.4 MB
    unsigned short* Gl  = (unsigned short*)((char*)B2 + (size_t)NNODES * 64 * 2);
    unsigned short* A3h = (unsigned short*)B1;                                    // A3 split, 25.6 MB each
    unsigned short* A3l = (unsigned short*)((char*)B1 + (size_t)NNODES * 256 * 2);
    unsigned short* Ah  = (unsigned short*)B1;                                    // A4 split, 12.8 MB each
    unsigned short* Al  = (unsigned short*)((char*)B1 + (size_t)NNODES * 128 * 2);

    const int* src = ei;
    const int* dst = ei + NEDGES;

    const int gN = (NNODES + 255) / 256;   // 196
    const int gE = (NEDGES + 255) / 256;

    k_init_cnt<<<gN, 256, 0, stream>>>(cnt);
    k_count<<<gE, 256, 0, stream>>>(dst, cnt);
    k_dinv<<<gN, 256, 0, stream>>>(cnt, dinv);
    k_bsum<<<gN, 256, 0, stream>>>(cnt, bsum);
    k_bscan<<<1, 256, 0, stream>>>(bsum, gN);
    k_rowptr<<<gN, 256, 0, stream>>>(cnt, bsum, rowptr);
    k_fill<<<gE, 256, 0, stream>>>(src, dst, rowptr, cnt, dinv, col, val);
    // weight splits for the MFMA decoder (no pipeline deps; tiny)
    k_wsplit<<<(128 * 1024 + 255) / 256, 256, 0, stream>>>(dWf, Wfh, Wfl, 128, 1024);
    k_wsplit<<<(64 * 256 + 255) / 256, 256, 0, stream>>>(dW1, W1h, W1l, 64, 256);
    k_wsplit<<<(256 * 128 + 255) / 256, 256, 0, stream>>>(dW2, W2h, W2l, 256, 128);

    const int MB = (NNODES + 127) / 128;   // 391 row-blocks

    // ---- Encoder (fp32 path) ----
    // H1 = x @ eW1 -> B1
    k_gemm<128,128,16,8,8,false,false><<<MB, 256, 0, stream>>>(x, eW1, nullptr, B1, NNODES, 128, 128, 1);
    // A1 = relu(agg(H1) + eb1) -> B2   (agg at 128 ch)
    k_spmm<128,true,true,false><<<(NNODES * 32 + 255) / 256, 256, 0, stream>>>(B1, dinv, rowptr, col, val, eb1, B2, nullptr, nullptr);
    // H2 = A1 @ eW2 -> B1
    k_gemm<128,64,16,8,4,false,false><<<MB, 256, 0, stream>>>(B2, eW2, nullptr, B1, NNODES, 64, 128, 1);
    // A2 = agg(H2) + eb2 -> B2         (agg at 64 ch)
    k_spmm<64,false,true,false><<<(NNODES * 16 + 255) / 256, 256, 0, stream>>>(B1, dinv, rowptr, col, val, eb2, B2, nullptr, nullptr);
    // Z = A2 @ eWf + ebf -> B1  [50000,64]
    k_gemm<128,64,16,8,4,false,false><<<MB, 256, 0, stream>>>(B2, eWf, ebf, B1, NNODES, 64, 64, 1);

    // ---- Decoder (MFMA bf16-split path) ----
    // G = agg(Z), bf16-split -> Gh/Gl in B2 (A2 dead)
    k_spmm<64,false,false,true><<<(NNODES * 16 + 255) / 256, 256, 0, stream>>>(B1, dinv, rowptr, col, val, nullptr, nullptr, Gh, Gl);
    // A3 = relu(G @ dW1 + db1), bf16-split -> A3h/A3l in B1 (Z dead)  [K=64, N=256]
    k_mfma<64,true,true,false><<<MB * 2, 256, 0, stream>>>(Gh, Gl, W1h, W1l, db1, nullptr, A3h, A3l, NNODES, 256);
    // H4 = A3 @ dW2, fp32 -> B2 (G dead)  [K=256, N=128]
    k_mfma<256,false,false,false><<<MB, 256, 0, stream>>>(A3h, A3l, W2h, W2l, nullptr, B2, nullptr, nullptr, NNODES, 128);
    // A4 = agg(H4) + db2, bf16-split -> Ah/Al in B1 (A3 dead)
    k_spmm<128,false,true,true><<<(NNODES * 32 + 255) / 256, 256, 0, stream>>>(B2, dinv, rowptr, col, val, db2, nullptr, Ah, Al);
    // x_hat = A4 @ dWf + dbf -> d_out  [K=128, N=1024]  (nontemporal stores;
    // B2 region of out is fully overwritten here, after its last read above)
    k_mfma<128,false,false,true><<<MB * 8, 256, 0, stream>>>(Ah, Al, Wfh, Wfl, dbf, out, nullptr, nullptr, NNODES, 1024);
}